// Round 17
// baseline (98.649 us; speedup 1.0000x reference)
//
#include <hip/hip_runtime.h>

// Problem constants: B=64, Cin=512, Cout=512, H=W=28 (HW=784), K=8 experts.
#define NB 64
#define CIN 512
#define COUT 512
#define HW 784
#define KEXP 8

typedef __attribute__((ext_vector_type(8))) short bf16x8;   // 8 bf16 = 4 VGPR (MFMA A/B frag)
typedef __attribute__((ext_vector_type(4))) float f32x4;    // MFMA C/D frag

__device__ __forceinline__ unsigned f2bf1(float f) {
  unsigned u = __builtin_bit_cast(unsigned, f);
  return (u + 0x7FFFu + ((u >> 16) & 1u)) >> 16;   // RNE fp32->bf16
}
__device__ __forceinline__ unsigned f2bf2(float lo, float hi) {
  return f2bf1(lo) | (f2bf1(hi) << 16);
}

// ---------------- Kernel 1: pooled[b][c] = mean(x[b][c][:,:]) --------------
// one wave per (b,c) row; 32768 rows; 8192 blocks x 4 waves.
__global__ __launch_bounds__(256) void pool_kernel(const float* __restrict__ x,
                                                   float* __restrict__ pooled) {
  int w = threadIdx.x >> 6, lane = threadIdx.x & 63;
  int row = blockIdx.x * 4 + w;                     // < 32768
  const float4* xr = (const float4*)(x + (size_t)row * HW);
  float s = 0.f;
  for (int i = lane; i < 196; i += 64) {
    float4 v = xr[i];
    s += (v.x + v.y) + (v.z + v.w);
  }
  #pragma unroll
  for (int off = 32; off; off >>= 1) s += __shfl_down(s, off);
  if (lane == 0) pooled[row] = s * (1.0f / 784.0f);
}

// ---------------- Kernel 2: gate (per-batch block) + local sparsemax -------
__global__ __launch_bounds__(256) void gate_kernel(const float* __restrict__ pooled,
                                                   const float* __restrict__ gw,
                                                   const float* __restrict__ gb,
                                                   float* __restrict__ g) {
  __shared__ float red[4][KEXP];
  int b = blockIdx.x;
  int t = threadIdx.x;
  int lane = t & 63, w = t >> 6;

  float p0 = pooled[b * CIN + t];
  float p1 = pooled[b * CIN + t + 256];
  float zk[KEXP];
  #pragma unroll
  for (int k = 0; k < KEXP; ++k)
    zk[k] = p0 * gw[k * CIN + t] + p1 * gw[k * CIN + t + 256];

  #pragma unroll
  for (int k = 0; k < KEXP; ++k) {
    float s = zk[k];
    #pragma unroll
    for (int off = 32; off; off >>= 1) s += __shfl_down(s, off);
    if (lane == 0) red[w][k] = s;
  }
  __syncthreads();

  if (t == 0) {
    float z[8], zs[8];
    #pragma unroll
    for (int j = 0; j < 8; ++j) {
      z[j] = (red[0][j] + red[1][j] + red[2][j] + red[3][j]) + gb[j];
      zs[j] = z[j];
    }
    #pragma unroll
    for (int a = 1; a < 8; ++a) {
      float v = zs[a]; int j = a;
      while (j > 0 && zs[j - 1] < v) { zs[j] = zs[j - 1]; --j; }
      zs[j] = v;
    }
    float cums[8]; float csum = 0.f;
    #pragma unroll
    for (int j = 0; j < 8; ++j) { csum += zs[j]; cums[j] = csum; }
    int kz = 0;
    #pragma unroll
    for (int j = 0; j < 8; ++j)
      if (1.0f + (float)(j + 1) * zs[j] > cums[j]) kz = j + 1;
    float tau = (cums[kz - 1] - 1.0f) / (float)kz;
    #pragma unroll
    for (int j = 0; j < 8; ++j) g[b * 8 + j] = fmaxf(z[j] - tau, 0.0f);
  }
}

// ---------------- Kernel 3: w_eff builder (bf16, BM=256 GEMM-tiled) -------
// unit(b,o,i) = b*32768 + ((o>>8)*16 + (i>>5))*1024 + ((i>>3)&3)*256 + (o&255)
__global__ __launch_bounds__(256) void weff_kernel(const float* __restrict__ E,
                                                   const float* __restrict__ g,
                                                   uint4* __restrict__ wt) {
  __shared__ float gs[NB * KEXP];
  int t = threadIdx.x;
  ((float2*)gs)[t] = ((const float2*)g)[t];
  int o = blockIdx.x * 16 + (t & 15);
  int i = blockIdx.y * 128 + (t >> 4) * 8;
  int b0 = blockIdx.z * 32;
  float e[8][8];
  #pragma unroll
  for (int k = 0; k < 8; ++k) {
    const float4* p = (const float4*)(E + (size_t)k * (COUT * CIN) + (size_t)o * CIN + i);
    float4 a = p[0], c = p[1];
    e[k][0] = a.x; e[k][1] = a.y; e[k][2] = a.z; e[k][3] = a.w;
    e[k][4] = c.x; e[k][5] = c.y; e[k][6] = c.z; e[k][7] = c.w;
  }
  __syncthreads();
  int base = ((o >> 8) * 16 + (i >> 5)) * 1024 + ((i >> 3) & 3) * 256 + (o & 255);
  for (int b = b0; b < b0 + 32; ++b) {
    float acc[8] = {0, 0, 0, 0, 0, 0, 0, 0};
    #pragma unroll
    for (int k = 0; k < 8; ++k) {
      float gv = gs[b * 8 + k];
      #pragma unroll
      for (int j = 0; j < 8; ++j) acc[j] += gv * e[k][j];
    }
    uint4 pk;
    pk.x = f2bf2(acc[0], acc[1]); pk.y = f2bf2(acc[2], acc[3]);
    pk.z = f2bf2(acc[4], acc[5]); pk.w = f2bf2(acc[6], acc[7]);
    wt[(size_t)base + (size_t)b * 32768] = pk;
  }
}

// ---------------- Kernel 4: batched GEMM, BM=256 x BN=112, BK=32 ----------
// R14 skeleton restructured into 2-tile SUPER-ITERATIONS (8 total):
//   pack tiles 2S,2S+1 -> ldsB[0],ldsB[1]; issue B(2S+2),B(2S+3) into the
//   just-consumed Bv slots; lgkm-only barrier; MFMA buf0; reissue A(2S+2);
//   MFMA buf1; reissue A(2S+3); plain s_barrier (each wave's ds_reads
//   completed before its last MFMA issued -> no waitcnt needed).
// Prefetch window doubles to a full super-iter (covers ~900cyc cold-HBM weff
// reads); lgkm-drain points halve; register footprint identical to R14
// (Bv[2][8], a2[2][2] -- no new buffers for the compiler to sink, the R15
// failure mode).
__global__ __launch_bounds__(512) void gemm_kernel(const uint4* __restrict__ weff,
                                                   const float* __restrict__ x,
                                                   float* __restrict__ out) {
  __shared__ uint4 ldsB[2][448];   // [kgrp4][col112] units, XOR-swizzled
  int id = blockIdx.x;
  int xcd = id & 7, s = id >> 3;
  int bloc = s / 14, inner = s - bloc * 14;
  int b = xcd * 8 + bloc;
  int mb = inner & 1, nb = inner >> 1;

  int t = threadIdx.x;
  int lane = t & 63, w = t >> 6;          // 8 waves
  int l15 = lane & 15, l4 = lane >> 4;

  const uint4* asrc = weff + (size_t)b * 32768 + (size_t)mb * 16384
                      + l4 * 256 + w * 32 + l15;
  // B: thread t<448 owns unit u=t: kgrp=u/112, col=u%112; loads 8 rows/tile.
  int u = t;
  int kgrp = u / 112, col = u - kgrp * 112;
  const float* xp = x + (size_t)b * (CIN * HW) + (size_t)kgrp * 8 * HW
                    + (size_t)nb * 112 + col;
  int uswz = u ^ ((u >> 3) & 7);

  f32x4 acc[2][7] = {};
  uint4 a2[2][2];
  float Bv[2][8];

  // prologue: tiles 0 and 1 in flight
  if (w < 7) {
    #pragma unroll
    for (int j = 0; j < 8; ++j) Bv[0][j] = xp[(size_t)j * HW];
    #pragma unroll
    for (int j = 0; j < 8; ++j) Bv[1][j] = xp[(size_t)32 * HW + (size_t)j * HW];
  }
  a2[0][0] = asrc[0];
  a2[0][1] = asrc[16];
  a2[1][0] = asrc[1024];
  a2[1][1] = asrc[1024 + 16];

  #pragma unroll
  for (int S = 0; S < 8; ++S) {
    const int k0 = 2 * S, k1 = 2 * S + 1;

    // pack both tiles (compiler vmcnt-waits each tile's regs)
    if (w < 7) {
      uint4 pk;
      pk.x = f2bf2(Bv[0][0], Bv[0][1]); pk.y = f2bf2(Bv[0][2], Bv[0][3]);
      pk.z = f2bf2(Bv[0][4], Bv[0][5]); pk.w = f2bf2(Bv[0][6], Bv[0][7]);
      ldsB[0][uswz] = pk;
      uint4 qk;
      qk.x = f2bf2(Bv[1][0], Bv[1][1]); qk.y = f2bf2(Bv[1][2], Bv[1][3]);
      qk.z = f2bf2(Bv[1][4], Bv[1][5]); qk.w = f2bf2(Bv[1][6], Bv[1][7]);
      ldsB[1][uswz] = qk;
      // issue next super-iter's B tiles into the just-consumed slots (WAR)
      if (S < 7) {
        #pragma unroll
        for (int j = 0; j < 8; ++j)
          Bv[0][j] = xp[(size_t)(k0 + 2) * 32 * HW + (size_t)j * HW];
        #pragma unroll
        for (int j = 0; j < 8; ++j)
          Bv[1][j] = xp[(size_t)(k1 + 2) * 32 * HW + (size_t)j * HW];
      }
    }

    // heavy barrier: ds_writes visible; global prefetch NOT drained
    asm volatile("s_waitcnt lgkmcnt(0)" ::: "memory");
    __builtin_amdgcn_s_barrier();
    __builtin_amdgcn_sched_barrier(0);

    // MFMA buffer 0 (tile k0), then reissue A(k0+2) into a2[0]
    {
      bf16x8 af0 = __builtin_bit_cast(bf16x8, a2[0][0]);
      bf16x8 af1 = __builtin_bit_cast(bf16x8, a2[0][1]);
      #pragma unroll
      for (int uu = 0; uu < 7; ++uu) {
        int un = l4 * 112 + uu * 16 + l15;
        bf16x8 bf = *(const bf16x8*)&ldsB[0][un ^ ((un >> 3) & 7)];
        acc[0][uu] = __builtin_amdgcn_mfma_f32_16x16x32_bf16(af0, bf, acc[0][uu], 0, 0, 0);
        acc[1][uu] = __builtin_amdgcn_mfma_f32_16x16x32_bf16(af1, bf, acc[1][uu], 0, 0, 0);
      }
      if (S < 7) {
        a2[0][0] = asrc[(k0 + 2) * 1024];
        a2[0][1] = asrc[(k0 + 2) * 1024 + 16];
      }
    }
    // MFMA buffer 1 (tile k1), then reissue A(k1+2) into a2[1]
    {
      bf16x8 af0 = __builtin_bit_cast(bf16x8, a2[1][0]);
      bf16x8 af1 = __builtin_bit_cast(bf16x8, a2[1][1]);
      #pragma unroll
      for (int uu = 0; uu < 7; ++uu) {
        int un = l4 * 112 + uu * 16 + l15;
        bf16x8 bf = *(const bf16x8*)&ldsB[1][un ^ ((un >> 3) & 7)];
        acc[0][uu] = __builtin_amdgcn_mfma_f32_16x16x32_bf16(af0, bf, acc[0][uu], 0, 0, 0);
        acc[1][uu] = __builtin_amdgcn_mfma_f32_16x16x32_bf16(af1, bf, acc[1][uu], 0, 0, 0);
      }
      if (S < 7) {
        a2[1][0] = asrc[(k1 + 2) * 1024];
        a2[1][1] = asrc[(k1 + 2) * 1024 + 16];
      }
    }

    // light barrier: protect ldsB from next super-iter's packs. No waitcnt
    // needed: each wave's ds_reads completed before its last MFMA issued.
    __builtin_amdgcn_s_barrier();
    __builtin_amdgcn_sched_barrier(0);
  }

  // epilogue: D layout col=lane&15, row=(lane>>4)*4+reg
  int orow0 = mb * 256 + w * 32 + l4 * 4;
  int ocol = nb * 112 + l15;
  #pragma unroll
  for (int m = 0; m < 2; ++m) {
    #pragma unroll
    for (int uu = 0; uu < 7; ++uu) {
      float* op = out + ((size_t)b * COUT + orow0 + m * 16) * HW + ocol + uu * 16;
      #pragma unroll
      for (int r = 0; r < 4; ++r) op[(size_t)r * HW] = acc[m][uu][r];
    }
  }
}

// ---------------- launcher -------------------------------------------------
extern "C" void kernel_launch(void* const* d_in, const int* in_sizes, int n_in,
                              void* d_out, int out_size, void* d_ws, size_t ws_size,
                              hipStream_t stream) {
  const float* x        = (const float*)d_in[0];
  const float* gate_w   = (const float*)d_in[1];
  const float* gate_b   = (const float*)d_in[2];
  const float* expert_w = (const float*)d_in[3];
  float* out = (float*)d_out;

  char* ws = (char*)d_ws;
  uint4* weff   = (uint4*)ws;                               // 33,554,432 B
  float* pooled = (float*)(ws + 33554432);                  //    131,072 B
  float* g      = (float*)(ws + 33554432 + 131072);         //      2,048 B

  pool_kernel<<<8192, 256, 0, stream>>>(x, pooled);
  gate_kernel<<<NB, 256, 0, stream>>>(pooled, gate_w, gate_b, g);
  weff_kernel<<<dim3(32, 4, 2), 256, 0, stream>>>(expert_w, g, weff);
  gemm_kernel<<<896, 512, 0, stream>>>(weff, x, out);
}

// Round 18
// 81.818 us; speedup vs baseline: 1.2057x; 1.2057x over previous
//
#include <hip/hip_runtime.h>

// Problem constants: B=64, Cin=512, Cout=512, H=W=28 (HW=784), K=8 experts.
#define NB 64
#define CIN 512
#define COUT 512
#define HW 784
#define KEXP 8

typedef __attribute__((ext_vector_type(8))) short bf16x8;   // 8 bf16 = 4 VGPR (MFMA A/B frag)
typedef __attribute__((ext_vector_type(4))) float f32x4;    // MFMA C/D frag

__device__ __forceinline__ unsigned f2bf1(float f) {
  unsigned u = __builtin_bit_cast(unsigned, f);
  return (u + 0x7FFFu + ((u >> 16) & 1u)) >> 16;   // RNE fp32->bf16
}
__device__ __forceinline__ unsigned f2bf2(float lo, float hi) {
  return f2bf1(lo) | (f2bf1(hi) << 16);
}

// ---------------- Kernel 1: pooled[b][c] = mean(x[b][c][:,:]) --------------
// one wave per (b,c) row; 32768 rows; 8192 blocks x 4 waves.
__global__ __launch_bounds__(256) void pool_kernel(const float* __restrict__ x,
                                                   float* __restrict__ pooled) {
  int w = threadIdx.x >> 6, lane = threadIdx.x & 63;
  int row = blockIdx.x * 4 + w;                     // < 32768
  const float4* xr = (const float4*)(x + (size_t)row * HW);
  float s = 0.f;
  for (int i = lane; i < 196; i += 64) {
    float4 v = xr[i];
    s += (v.x + v.y) + (v.z + v.w);
  }
  #pragma unroll
  for (int off = 32; off; off >>= 1) s += __shfl_down(s, off);
  if (lane == 0) pooled[row] = s * (1.0f / 784.0f);
}

// ---------------- Kernel 2: gate (per-batch block) + local sparsemax -------
__global__ __launch_bounds__(256) void gate_kernel(const float* __restrict__ pooled,
                                                   const float* __restrict__ gw,
                                                   const float* __restrict__ gb,
                                                   float* __restrict__ g) {
  __shared__ float red[4][KEXP];
  int b = blockIdx.x;
  int t = threadIdx.x;
  int lane = t & 63, w = t >> 6;

  float p0 = pooled[b * CIN + t];
  float p1 = pooled[b * CIN + t + 256];
  float zk[KEXP];
  #pragma unroll
  for (int k = 0; k < KEXP; ++k)
    zk[k] = p0 * gw[k * CIN + t] + p1 * gw[k * CIN + t + 256];

  #pragma unroll
  for (int k = 0; k < KEXP; ++k) {
    float s = zk[k];
    #pragma unroll
    for (int off = 32; off; off >>= 1) s += __shfl_down(s, off);
    if (lane == 0) red[w][k] = s;
  }
  __syncthreads();

  if (t == 0) {
    float z[8], zs[8];
    #pragma unroll
    for (int j = 0; j < 8; ++j) {
      z[j] = (red[0][j] + red[1][j] + red[2][j] + red[3][j]) + gb[j];
      zs[j] = z[j];
    }
    #pragma unroll
    for (int a = 1; a < 8; ++a) {
      float v = zs[a]; int j = a;
      while (j > 0 && zs[j - 1] < v) { zs[j] = zs[j - 1]; --j; }
      zs[j] = v;
    }
    float cums[8]; float csum = 0.f;
    #pragma unroll
    for (int j = 0; j < 8; ++j) { csum += zs[j]; cums[j] = csum; }
    int kz = 0;
    #pragma unroll
    for (int j = 0; j < 8; ++j)
      if (1.0f + (float)(j + 1) * zs[j] > cums[j]) kz = j + 1;
    float tau = (cums[kz - 1] - 1.0f) / (float)kz;
    #pragma unroll
    for (int j = 0; j < 8; ++j) g[b * 8 + j] = fmaxf(z[j] - tau, 0.0f);
  }
}

// ---------------- Kernel 3: w_eff builder (bf16, BM=256 GEMM-tiled) -------
// unit(b,o,i) = b*32768 + ((o>>8)*16 + (i>>5))*1024 + ((i>>3)&3)*256 + (o&255)
__global__ __launch_bounds__(256) void weff_kernel(const float* __restrict__ E,
                                                   const float* __restrict__ g,
                                                   uint4* __restrict__ wt) {
  __shared__ float gs[NB * KEXP];
  int t = threadIdx.x;
  ((float2*)gs)[t] = ((const float2*)g)[t];
  int o = blockIdx.x * 16 + (t & 15);
  int i = blockIdx.y * 128 + (t >> 4) * 8;
  int b0 = blockIdx.z * 32;
  float e[8][8];
  #pragma unroll
  for (int k = 0; k < 8; ++k) {
    const float4* p = (const float4*)(E + (size_t)k * (COUT * CIN) + (size_t)o * CIN + i);
    float4 a = p[0], c = p[1];
    e[k][0] = a.x; e[k][1] = a.y; e[k][2] = a.z; e[k][3] = a.w;
    e[k][4] = c.x; e[k][5] = c.y; e[k][6] = c.z; e[k][7] = c.w;
  }
  __syncthreads();
  int base = ((o >> 8) * 16 + (i >> 5)) * 1024 + ((i >> 3) & 3) * 256 + (o & 255);
  for (int b = b0; b < b0 + 32; ++b) {
    float acc[8] = {0, 0, 0, 0, 0, 0, 0, 0};
    #pragma unroll
    for (int k = 0; k < 8; ++k) {
      float gv = gs[b * 8 + k];
      #pragma unroll
      for (int j = 0; j < 8; ++j) acc[j] += gv * e[k][j];
    }
    uint4 pk;
    pk.x = f2bf2(acc[0], acc[1]); pk.y = f2bf2(acc[2], acc[3]);
    pk.z = f2bf2(acc[4], acc[5]); pk.w = f2bf2(acc[6], acc[7]);
    wt[(size_t)base + (size_t)b * 32768] = pk;
  }
}

// ---------------- Kernel 4: batched GEMM, BM=256 x BN=112, BK=32 ----------
// R14's proven K-loop verbatim (compiler-tracked loads, depth-1 reg prefetch,
// lgkm-only raw barrier). NEW: LDS-transpose epilogue — ldsB reused as a
// 32-row x 112-float staging buffer (14336 B exactly); 8 phases (m x reg r):
// waves deposit 4-row slices, barrier, 896 float4 stored as 448B-contiguous
// runs (vs the fragment-direct 64B segments = half-efficiency HBM writes).
__global__ __launch_bounds__(512) void gemm_kernel(const uint4* __restrict__ weff,
                                                   const float* __restrict__ x,
                                                   float* __restrict__ out) {
  __shared__ uint4 ldsB[2][448];   // [kgrp4][col112] units, XOR-swizzled
  int id = blockIdx.x;
  int xcd = id & 7, s = id >> 3;
  int bloc = s / 14, inner = s - bloc * 14;
  int b = xcd * 8 + bloc;
  int mb = inner & 1, nb = inner >> 1;

  int t = threadIdx.x;
  int lane = t & 63, w = t >> 6;          // 8 waves
  int l15 = lane & 15, l4 = lane >> 4;

  const uint4* asrc = weff + (size_t)b * 32768 + (size_t)mb * 16384
                      + l4 * 256 + w * 32 + l15;
  // B: thread t<448 owns unit u=t: kgrp=u/112, col=u%112; loads 8 rows/tile.
  int u = t;
  int kgrp = u / 112, col = u - kgrp * 112;
  const float* xp = x + (size_t)b * (CIN * HW) + (size_t)kgrp * 8 * HW
                    + (size_t)nb * 112 + col;
  int uswz = u ^ ((u >> 3) & 7);

  f32x4 acc[2][7] = {};
  uint4 a2[2][2];
  float Bv[2][8];

  // prologue: tile 0 to regs (compiler inserts waits before first use)
  if (w < 7) {
    #pragma unroll
    for (int j = 0; j < 8; ++j) Bv[0][j] = xp[(size_t)j * HW];
  }
  a2[0][0] = asrc[0];
  a2[0][1] = asrc[16];

  #pragma unroll
  for (int kk = 0; kk < 16; ++kk) {
    // pack tile kk into ldsB[kk&1] (compiler waits on Bv[kk&1] regs only)
    if (w < 7) {
      uint4 pk;
      pk.x = f2bf2(Bv[kk & 1][0], Bv[kk & 1][1]);
      pk.y = f2bf2(Bv[kk & 1][2], Bv[kk & 1][3]);
      pk.z = f2bf2(Bv[kk & 1][4], Bv[kk & 1][5]);
      pk.w = f2bf2(Bv[kk & 1][6], Bv[kk & 1][7]);
      ldsB[kk & 1][uswz] = pk;
    }
    // prefetch tile kk+1 — stays in flight across the barrier below
    if (kk < 15) {
      if (w < 7) {
        #pragma unroll
        for (int j = 0; j < 8; ++j)
          Bv[(kk + 1) & 1][j] = xp[(size_t)(kk + 1) * 32 * HW + (size_t)j * HW];
      }
      a2[(kk + 1) & 1][0] = asrc[(kk + 1) * 1024];
      a2[(kk + 1) & 1][1] = asrc[(kk + 1) * 1024 + 16];
    }

    // lgkm-only barrier: pack visible to all, prefetch NOT drained
    asm volatile("s_waitcnt lgkmcnt(0)" ::: "memory");
    __builtin_amdgcn_s_barrier();
    __builtin_amdgcn_sched_barrier(0);

    bf16x8 af0 = __builtin_bit_cast(bf16x8, a2[kk & 1][0]);
    bf16x8 af1 = __builtin_bit_cast(bf16x8, a2[kk & 1][1]);
    #pragma unroll
    for (int uu = 0; uu < 7; ++uu) {
      int un = l4 * 112 + uu * 16 + l15;
      bf16x8 bf = *(const bf16x8*)&ldsB[kk & 1][un ^ ((un >> 3) & 7)];
      acc[0][uu] = __builtin_amdgcn_mfma_f32_16x16x32_bf16(af0, bf, acc[0][uu], 0, 0, 0);
      acc[1][uu] = __builtin_amdgcn_mfma_f32_16x16x32_bf16(af1, bf, acc[1][uu], 0, 0, 0);
    }
  }

  // ---------------- LDS-transpose epilogue ----------------
  // ldsB reused as float[3584] = 32 rows x 112 cols. Phase (m, r): wave w
  // deposits rows {w*32 + m*16 + l4*4 + r}; after barrier, 896 float4 units
  // are stored as 28-unit (448B) contiguous runs per row.
  float* eps = (float*)ldsB;
  __syncthreads();   // all waves' K-loop LDS reads done before overwrite

  #pragma unroll
  for (int m = 0; m < 2; ++m) {
    #pragma unroll
    for (int r = 0; r < 4; ++r) {
      #pragma unroll
      for (int uu = 0; uu < 7; ++uu)
        eps[w * 448 + l4 * 112 + uu * 16 + l15] = acc[m][uu][r];
      __syncthreads();
      {
        int cr = t >> 5;                 // wait: need u/28 — compute directly
      }
      // 896 float4 units: unit q -> chunkrow q/28, col4 q%28
      {
        int q = t, cr = q / 28, c4 = q - cr * 28;
        int orow = mb * 256 + (cr >> 2) * 32 + m * 16 + (cr & 3) * 4 + r;
        float4 v = *(const float4*)&eps[cr * 112 + c4 * 4];
        *(float4*)(out + ((size_t)b * COUT + orow) * HW + nb * 112 + c4 * 4) = v;
      }
      if (t < 384) {
        int q = t + 512, cr = q / 28, c4 = q - cr * 28;
        int orow = mb * 256 + (cr >> 2) * 32 + m * 16 + (cr & 3) * 4 + r;
        float4 v = *(const float4*)&eps[cr * 112 + c4 * 4];
        *(float4*)(out + ((size_t)b * COUT + orow) * HW + nb * 112 + c4 * 4) = v;
      }
      __syncthreads();
    }
  }
}

// ---------------- launcher -------------------------------------------------
extern "C" void kernel_launch(void* const* d_in, const int* in_sizes, int n_in,
                              void* d_out, int out_size, void* d_ws, size_t ws_size,
                              hipStream_t stream) {
  const float* x        = (const float*)d_in[0];
  const float* gate_w   = (const float*)d_in[1];
  const float* gate_b   = (const float*)d_in[2];
  const float* expert_w = (const float*)d_in[3];
  float* out = (float*)d_out;

  char* ws = (char*)d_ws;
  uint4* weff   = (uint4*)ws;                               // 33,554,432 B
  float* pooled = (float*)(ws + 33554432);                  //    131,072 B
  float* g      = (float*)(ws + 33554432 + 131072);         //      2,048 B

  pool_kernel<<<8192, 256, 0, stream>>>(x, pooled);
  gate_kernel<<<NB, 256, 0, stream>>>(pooled, gate_w, gate_b, g);
  weff_kernel<<<dim3(32, 4, 2), 256, 0, stream>>>(expert_w, g, weff);
  gemm_kernel<<<896, 512, 0, stream>>>(weff, x, out);
}

// Round 20
// 81.315 us; speedup vs baseline: 1.2132x; 1.0062x over previous
//
#include <hip/hip_runtime.h>
#include <hip/hip_bf16.h>

// Problem constants: B=64, Cin=512, Cout=512, H=W=28 (HW=784), K=8 experts.
#define NB 64
#define CIN 512
#define COUT 512
#define HW 784
#define KEXP 8

typedef __attribute__((ext_vector_type(8))) short bf16x8;   // 8 bf16 = 4 VGPR (MFMA A/B frag)
typedef __attribute__((ext_vector_type(4))) float f32x4;    // MFMA C/D frag

// fp32 pair -> packed bf16x2 (RNE). HIP intrinsic so the compiler emits
// v_cvt_pk_bf16_f32 (1 instr) instead of ~10 VALU ops of bit-twiddling.
// (__hip_bfloat162 is not trivially copyable -> memcpy, not bit_cast.)
__device__ __forceinline__ unsigned f2bf2(float lo, float hi) {
  __hip_bfloat162 h2 = __float22bfloat162_rn(float2{lo, hi});
  unsigned u;
  __builtin_memcpy(&u, &h2, 4);
  return u;
}

// ---------------- Kernel 1: pooled[b][c] = mean(x[b][c][:,:]) --------------
// one wave per (b,c) row; 32768 rows; 8192 blocks x 4 waves.
__global__ __launch_bounds__(256) void pool_kernel(const float* __restrict__ x,
                                                   float* __restrict__ pooled) {
  int w = threadIdx.x >> 6, lane = threadIdx.x & 63;
  int row = blockIdx.x * 4 + w;                     // < 32768
  const float4* xr = (const float4*)(x + (size_t)row * HW);
  float s = 0.f;
  for (int i = lane; i < 196; i += 64) {
    float4 v = xr[i];
    s += (v.x + v.y) + (v.z + v.w);
  }
  #pragma unroll
  for (int off = 32; off; off >>= 1) s += __shfl_down(s, off);
  if (lane == 0) pooled[row] = s * (1.0f / 784.0f);
}

// ---------------- Kernel 2: gate (per-batch block) + local sparsemax -------
__global__ __launch_bounds__(256) void gate_kernel(const float* __restrict__ pooled,
                                                   const float* __restrict__ gw,
                                                   const float* __restrict__ gb,
                                                   float* __restrict__ g) {
  __shared__ float red[4][KEXP];
  int b = blockIdx.x;
  int t = threadIdx.x;
  int lane = t & 63, w = t >> 6;

  float p0 = pooled[b * CIN + t];
  float p1 = pooled[b * CIN + t + 256];
  float zk[KEXP];
  #pragma unroll
  for (int k = 0; k < KEXP; ++k)
    zk[k] = p0 * gw[k * CIN + t] + p1 * gw[k * CIN + t + 256];

  #pragma unroll
  for (int k = 0; k < KEXP; ++k) {
    float s = zk[k];
    #pragma unroll
    for (int off = 32; off; off >>= 1) s += __shfl_down(s, off);
    if (lane == 0) red[w][k] = s;
  }
  __syncthreads();

  if (t == 0) {
    float z[8], zs[8];
    #pragma unroll
    for (int j = 0; j < 8; ++j) {
      z[j] = (red[0][j] + red[1][j] + red[2][j] + red[3][j]) + gb[j];
      zs[j] = z[j];
    }
    #pragma unroll
    for (int a = 1; a < 8; ++a) {
      float v = zs[a]; int j = a;
      while (j > 0 && zs[j - 1] < v) { zs[j] = zs[j - 1]; --j; }
      zs[j] = v;
    }
    float cums[8]; float csum = 0.f;
    #pragma unroll
    for (int j = 0; j < 8; ++j) { csum += zs[j]; cums[j] = csum; }
    int kz = 0;
    #pragma unroll
    for (int j = 0; j < 8; ++j)
      if (1.0f + (float)(j + 1) * zs[j] > cums[j]) kz = j + 1;
    float tau = (cums[kz - 1] - 1.0f) / (float)kz;
    #pragma unroll
    for (int j = 0; j < 8; ++j) g[b * 8 + j] = fmaxf(z[j] - tau, 0.0f);
  }
}

// ---------------- Kernel 3: w_eff builder (bf16, BM=256 GEMM-tiled) -------
// unit(b,o,i) = b*32768 + ((o>>8)*16 + (i>>5))*1024 + ((i>>3)&3)*256 + (o&255)
__global__ __launch_bounds__(256) void weff_kernel(const float* __restrict__ E,
                                                   const float* __restrict__ g,
                                                   uint4* __restrict__ wt) {
  __shared__ float gs[NB * KEXP];
  int t = threadIdx.x;
  ((float2*)gs)[t] = ((const float2*)g)[t];
  int o = blockIdx.x * 16 + (t & 15);
  int i = blockIdx.y * 128 + (t >> 4) * 8;
  int b0 = blockIdx.z * 32;
  float e[8][8];
  #pragma unroll
  for (int k = 0; k < 8; ++k) {
    const float4* p = (const float4*)(E + (size_t)k * (COUT * CIN) + (size_t)o * CIN + i);
    float4 a = p[0], c = p[1];
    e[k][0] = a.x; e[k][1] = a.y; e[k][2] = a.z; e[k][3] = a.w;
    e[k][4] = c.x; e[k][5] = c.y; e[k][6] = c.z; e[k][7] = c.w;
  }
  __syncthreads();
  int base = ((o >> 8) * 16 + (i >> 5)) * 1024 + ((i >> 3) & 3) * 256 + (o & 255);
  for (int b = b0; b < b0 + 32; ++b) {
    float acc[8] = {0, 0, 0, 0, 0, 0, 0, 0};
    #pragma unroll
    for (int k = 0; k < 8; ++k) {
      float gv = gs[b * 8 + k];
      #pragma unroll
      for (int j = 0; j < 8; ++j) acc[j] += gv * e[k][j];
    }
    uint4 pk;
    pk.x = f2bf2(acc[0], acc[1]); pk.y = f2bf2(acc[2], acc[3]);
    pk.z = f2bf2(acc[4], acc[5]); pk.w = f2bf2(acc[6], acc[7]);
    wt[(size_t)base + (size_t)b * 32768] = pk;
  }
}

// ---------------- Kernel 4: batched GEMM, BM=256 x BN=112, BK=32 ----------
// R14's proven K-loop (compiler-tracked loads, depth-1 reg prefetch,
// lgkm-only raw barrier) + LDS-transpose epilogue (R18). Pack uses
// v_cvt_pk_bf16_f32 via f2bf2 (the one change this round).
__global__ __launch_bounds__(512) void gemm_kernel(const uint4* __restrict__ weff,
                                                   const float* __restrict__ x,
                                                   float* __restrict__ out) {
  __shared__ uint4 ldsB[2][448];   // [kgrp4][col112] units, XOR-swizzled
  int id = blockIdx.x;
  int xcd = id & 7, s = id >> 3;
  int bloc = s / 14, inner = s - bloc * 14;
  int b = xcd * 8 + bloc;
  int mb = inner & 1, nb = inner >> 1;

  int t = threadIdx.x;
  int lane = t & 63, w = t >> 6;          // 8 waves
  int l15 = lane & 15, l4 = lane >> 4;

  const uint4* asrc = weff + (size_t)b * 32768 + (size_t)mb * 16384
                      + l4 * 256 + w * 32 + l15;
  // B: thread t<448 owns unit u=t: kgrp=u/112, col=u%112; loads 8 rows/tile.
  int u = t;
  int kgrp = u / 112, col = u - kgrp * 112;
  const float* xp = x + (size_t)b * (CIN * HW) + (size_t)kgrp * 8 * HW
                    + (size_t)nb * 112 + col;
  int uswz = u ^ ((u >> 3) & 7);

  f32x4 acc[2][7] = {};
  uint4 a2[2][2];
  float Bv[2][8];

  // prologue: tile 0 to regs (compiler inserts waits before first use)
  if (w < 7) {
    #pragma unroll
    for (int j = 0; j < 8; ++j) Bv[0][j] = xp[(size_t)j * HW];
  }
  a2[0][0] = asrc[0];
  a2[0][1] = asrc[16];

  #pragma unroll
  for (int kk = 0; kk < 16; ++kk) {
    // pack tile kk into ldsB[kk&1] (compiler waits on Bv[kk&1] regs only)
    if (w < 7) {
      uint4 pk;
      pk.x = f2bf2(Bv[kk & 1][0], Bv[kk & 1][1]);
      pk.y = f2bf2(Bv[kk & 1][2], Bv[kk & 1][3]);
      pk.z = f2bf2(Bv[kk & 1][4], Bv[kk & 1][5]);
      pk.w = f2bf2(Bv[kk & 1][6], Bv[kk & 1][7]);
      ldsB[kk & 1][uswz] = pk;
    }
    // prefetch tile kk+1 — stays in flight across the barrier below
    if (kk < 15) {
      if (w < 7) {
        #pragma unroll
        for (int j = 0; j < 8; ++j)
          Bv[(kk + 1) & 1][j] = xp[(size_t)(kk + 1) * 32 * HW + (size_t)j * HW];
      }
      a2[(kk + 1) & 1][0] = asrc[(kk + 1) * 1024];
      a2[(kk + 1) & 1][1] = asrc[(kk + 1) * 1024 + 16];
    }

    // lgkm-only barrier: pack visible to all, prefetch NOT drained
    asm volatile("s_waitcnt lgkmcnt(0)" ::: "memory");
    __builtin_amdgcn_s_barrier();
    __builtin_amdgcn_sched_barrier(0);

    bf16x8 af0 = __builtin_bit_cast(bf16x8, a2[kk & 1][0]);
    bf16x8 af1 = __builtin_bit_cast(bf16x8, a2[kk & 1][1]);
    #pragma unroll
    for (int uu = 0; uu < 7; ++uu) {
      int un = l4 * 112 + uu * 16 + l15;
      bf16x8 bf = *(const bf16x8*)&ldsB[kk & 1][un ^ ((un >> 3) & 7)];
      acc[0][uu] = __builtin_amdgcn_mfma_f32_16x16x32_bf16(af0, bf, acc[0][uu], 0, 0, 0);
      acc[1][uu] = __builtin_amdgcn_mfma_f32_16x16x32_bf16(af1, bf, acc[1][uu], 0, 0, 0);
    }
  }

  // ---------------- LDS-transpose epilogue ----------------
  // ldsB reused as float[3584] = 32 rows x 112 cols. Phase (m, r): wave w
  // deposits rows {w*32 + m*16 + l4*4 + r}; after barrier, 896 float4 units
  // are stored as 448B-contiguous runs per row.
  float* eps = (float*)ldsB;
  __syncthreads();   // all waves' K-loop LDS reads done before overwrite

  #pragma unroll
  for (int m = 0; m < 2; ++m) {
    #pragma unroll
    for (int r = 0; r < 4; ++r) {
      #pragma unroll
      for (int uu = 0; uu < 7; ++uu)
        eps[w * 448 + l4 * 112 + uu * 16 + l15] = acc[m][uu][r];
      __syncthreads();
      // 896 float4 units: unit q -> chunkrow q/28, col4 q%28
      {
        int q = t, cr = q / 28, c4 = q - cr * 28;
        int orow = mb * 256 + (cr >> 2) * 32 + m * 16 + (cr & 3) * 4 + r;
        float4 v = *(const float4*)&eps[cr * 112 + c4 * 4];
        *(float4*)(out + ((size_t)b * COUT + orow) * HW + nb * 112 + c4 * 4) = v;
      }
      if (t < 384) {
        int q = t + 512, cr = q / 28, c4 = q - cr * 28;
        int orow = mb * 256 + (cr >> 2) * 32 + m * 16 + (cr & 3) * 4 + r;
        float4 v = *(const float4*)&eps[cr * 112 + c4 * 4];
        *(float4*)(out + ((size_t)b * COUT + orow) * HW + nb * 112 + c4 * 4) = v;
      }
      __syncthreads();
    }
  }
}

// ---------------- launcher -------------------------------------------------
extern "C" void kernel_launch(void* const* d_in, const int* in_sizes, int n_in,
                              void* d_out, int out_size, void* d_ws, size_t ws_size,
                              hipStream_t stream) {
  const float* x        = (const float*)d_in[0];
  const float* gate_w   = (const float*)d_in[1];
  const float* gate_b   = (const float*)d_in[2];
  const float* expert_w = (const float*)d_in[3];
  float* out = (float*)d_out;

  char* ws = (char*)d_ws;
  uint4* weff   = (uint4*)ws;                               // 33,554,432 B
  float* pooled = (float*)(ws + 33554432);                  //    131,072 B
  float* g      = (float*)(ws + 33554432 + 131072);         //      2,048 B

  pool_kernel<<<8192, 256, 0, stream>>>(x, pooled);
  gate_kernel<<<NB, 256, 0, stream>>>(pooled, gate_w, gate_b, g);
  weff_kernel<<<dim3(32, 4, 2), 256, 0, stream>>>(expert_w, g, weff);
  gemm_kernel<<<896, 512, 0, stream>>>(weff, x, out);
}